// Round 15
// baseline (234.977 us; speedup 1.0000x reference)
//
#include <hip/hip_runtime.h>
#include <hip/hip_bf16.h>
#include <cstdint>

// Problem constants
#define BATCH 8
#define SEQ   1024          // LQ == LK
#define DMODEL 1024
#define NHEAD 8
#define DHEAD 128

using short8 = __attribute__((ext_vector_type(8))) short;
using f32x4  = __attribute__((ext_vector_type(4))) float;
typedef unsigned short u16;

__device__ inline u16 f2bf(float f) {
    union { float f; uint32_t u; } v; v.f = f;
    uint32_t r = (v.u + 0x7FFFu + ((v.u >> 16) & 1u)) >> 16;
    return (u16)r;
}

// native 2^x (v_exp_f32)
__device__ inline float exp2_fast(float x) { return __builtin_amdgcn_exp2f(x); }

// packed f32x2 -> bf16x2 (RNE), low half = a
__device__ inline uint32_t cvtpk_bf16(float a, float b) {
    uint32_t r;
    asm("v_cvt_pk_bf16_f32 %0, %1, %2" : "=v"(r) : "v"(a), "v"(b));
    return r;
}

// async global->LDS, 16B per lane. LDS dest is wave-uniform base; HW adds lane*16.
#define GLL16(g, l)                                                                        \
    __builtin_amdgcn_global_load_lds((__attribute__((address_space(1))) const uint32_t*)(g), \
                                     (__attribute__((address_space(3))) uint32_t*)(l), 16, 0, 0)

// ---------------------------------------------------------------------------
// Kernel 1: prep pass.
// z=0: Wq -> WqT ; z=1: Wk -> WkT ; z>=2: k[b] -> Vt[b] (transpose) AND
// k[b] -> kb[b] (bf16 copy) AND q[b] -> qb[b] (bf16 copy).
// ---------------------------------------------------------------------------
__global__ void transpose_conv(const float* __restrict__ Wq,
                               const float* __restrict__ Wk,
                               const float* __restrict__ kin,
                               const float* __restrict__ qin,
                               u16* __restrict__ WqT,
                               u16* __restrict__ WkT,
                               u16* __restrict__ Vt,
                               u16* __restrict__ kb,
                               u16* __restrict__ qb) {
    __shared__ float tile[32][33];
    int z = blockIdx.z;
    const float* src;
    u16* dst;
    u16* sdst = nullptr;
    const float* qsrc = nullptr;
    u16* qdst = nullptr;
    if (z == 0)      { src = Wq; dst = WqT; }
    else if (z == 1) { src = Wk; dst = WkT; }
    else {
        size_t off = (size_t)(z - 2) * DMODEL * SEQ;
        src  = kin + off;
        dst  = Vt  + off;
        sdst = kb  + off;
        qsrc = qin + off;
        qdst = qb  + off;
    }
    int x  = blockIdx.x * 32 + threadIdx.x;
    int y0 = blockIdx.y * 32;
    for (int i = threadIdx.y; i < 32; i += 8) {
        float v = src[(size_t)(y0 + i) * 1024 + x];
        tile[i][threadIdx.x] = v;
        if (sdst) sdst[(size_t)(y0 + i) * 1024 + x] = f2bf(v);
    }
    if (qsrc) {
        for (int i = threadIdx.y; i < 32; i += 8)
            qdst[(size_t)(y0 + i) * 1024 + x] = f2bf(qsrc[(size_t)(y0 + i) * 1024 + x]);
    }
    __syncthreads();
    int xo  = y0 + threadIdx.x;
    int yo0 = blockIdx.x * 32;
    for (int i = threadIdx.y; i < 32; i += 8)
        dst[(size_t)(yo0 + i) * 1024 + xo] = f2bf(tile[threadIdx.x][i]);
}

// ---------------------------------------------------------------------------
// Kernel 2: fused dual GEMM (m97 structure, proven). 128x128 tile, BK=32,
// both operands global_load_lds w16, dbuf, 1 barrier/iter, XOR swizzle.
// blocks 0..511: Q-proj (scale=log2e/sqrt(DH)); 512..1023: K-proj.
// ---------------------------------------------------------------------------
__global__ __launch_bounds__(256, 4) void gemm_dual(const u16* __restrict__ Aq,
                                                    const u16* __restrict__ Ak,
                                                    const u16* __restrict__ BTq,
                                                    const u16* __restrict__ BTk,
                                                    const float* __restrict__ biasq,
                                                    const float* __restrict__ biask,
                                                    u16* __restrict__ Outq,
                                                    u16* __restrict__ Outk) {
    __shared__ __align__(16) u16 As[2][128 * 32];
    __shared__ __align__(16) u16 Bs[2][128 * 32];

    int bid = blockIdx.x;
    int half = bid >> 9;
    int b2 = bid & 511;
    const u16* A  = half ? Ak  : Aq;
    const u16* BT = half ? BTk : BTq;
    const float* bias = half ? biask : biasq;
    u16* Out = half ? Outk : Outq;
    float scale = half ? 1.0f : (0.08838834764831845f * 1.4426950408889634f);

    int swz = (b2 & 7) * 64 + (b2 >> 3);
    int mt = swz >> 3, nt = swz & 7;
    int m0 = mt * 128, n0 = nt * 128;

    int t = threadIdx.x, lane = t & 63, w = t >> 6;
    int wm = w >> 1, wn = w & 1;
    int lr = lane & 15, lg = lane >> 4;

    const u16* pa[2];
    const u16* pb[2];
#pragma unroll
    for (int i = 0; i < 2; ++i) {
        int L = (w * 2 + i) * 64 + lane;
        int rp = L >> 3, ss = L & 7;
        int u = ss ^ (rp & 7);
        int row = (rp << 1) | (u >> 2);
        int g = u & 3;
        pa[i] = A  + (size_t)(m0 + row) * 1024 + g * 8;
        pb[i] = BT + (size_t)(n0 + row) * 1024 + g * 8;
    }
    int aoff[4], boff[4];
#pragma unroll
    for (int f = 0; f < 4; ++f) {
        int rowA = wm * 64 + f * 16 + lr;
        int sA = (((rowA & 1) << 2) | lg) ^ ((rowA >> 1) & 7);
        aoff[f] = (rowA >> 1) * 64 + sA * 8;
        int rowB = wn * 64 + f * 16 + lr;
        int sB = (((rowB & 1) << 2) | lg) ^ ((rowB >> 1) & 7);
        boff[f] = (rowB >> 1) * 64 + sB * 8;
    }

    f32x4 acc[4][4] = {};

#define GSTAGE(buf)                                         \
    {                                                       \
        _Pragma("unroll")                                   \
        for (int i = 0; i < 2; ++i) {                       \
            GLL16(pa[i], &As[buf][(w * 2 + i) * 512]);      \
            GLL16(pb[i], &Bs[buf][(w * 2 + i) * 512]);      \
            pa[i] += 32;                                    \
            pb[i] += 32;                                    \
        }                                                   \
    }

    GSTAGE(0);
    __syncthreads();

    int cur = 0;
    for (int k0 = 0; k0 < DMODEL; k0 += 32) {
        if (k0 + 32 < DMODEL) GSTAGE(cur ^ 1);
        short8 af[4], bfr[4];
#pragma unroll
        for (int f = 0; f < 4; ++f) {
            af[f]  = *(const short8*)&As[cur][aoff[f]];
            bfr[f] = *(const short8*)&Bs[cur][boff[f]];
        }
        __builtin_amdgcn_s_setprio(1);
#pragma unroll
        for (int fm = 0; fm < 4; ++fm)
#pragma unroll
            for (int fn = 0; fn < 4; ++fn)
                acc[fm][fn] = __builtin_amdgcn_mfma_f32_16x16x32_bf16(af[fm], bfr[fn], acc[fm][fn], 0, 0, 0);
        __builtin_amdgcn_s_setprio(0);
        __syncthreads();
        cur ^= 1;
    }
#undef GSTAGE

#pragma unroll
    for (int fn = 0; fn < 4; ++fn) {
        int col = n0 + wn * 64 + fn * 16 + lr;
        float bv = bias[col];
#pragma unroll
        for (int fm = 0; fm < 4; ++fm)
#pragma unroll
            for (int j = 0; j < 4; ++j) {
                int row = m0 + wm * 64 + fm * 16 + lg * 4 + j;
                Out[(size_t)row * 1024 + col] = f2bf((acc[fm][fn][j] + bv) * scale);
            }
    }
}

// ---------------------------------------------------------------------------
// Kernel 3: flash attention (r11 proven body). ONLY change: the per-wave P
// buffer is shared between q-sets A and B (write PA -> read pfA -> write PB
// -> read pfB; per-wave DS ordering + compiler lgkmcnt waits make this safe).
// LDS 98->80KB => 2 independent blocks/CU (cross-block phase drift: one
// block's softmax VALU overlaps the other's QK/PV MFMA).
// ---------------------------------------------------------------------------
__global__ __launch_bounds__(512, 4) void attn_kernel(const u16* __restrict__ Qb,
                                                      const u16* __restrict__ Kb,
                                                      const u16* __restrict__ Vt,
                                                      float* __restrict__ AO,
                                                      u16* __restrict__ AOb) {
    __shared__ __align__(16) u16 Kbuf[2][64 * 128];   // 32 KB
    __shared__ __align__(16) u16 Vbuf[2][128 * 64];   // 32 KB
    __shared__ __align__(16) u16 Pl[8][16 * 64];      // 16 KB  (80 KB total)

    int bid = blockIdx.x;
    int swz = (bid & 7) * 32 + (bid >> 3);
    int bh  = swz >> 2;
    int qt  = swz & 3;
    int b = bh >> 3, h = bh & 7;
    int q0 = qt * 256;

    int t = threadIdx.x, lane = t & 63, w = t >> 6;
    int lr = lane & 15, lg = lane >> 4;

    short8 qfA[4], qfB[4];
    {
        size_t qa = (size_t)(b * SEQ + q0 + w * 32 + lr) * 1024 + h * DHEAD;
        size_t qbB = qa + (size_t)16 * 1024;
#pragma unroll
        for (int kk = 0; kk < 4; ++kk) {
            qfA[kk] = *(const short8*)&Qb[qa  + kk * 32 + lg * 8];
            qfB[kk] = *(const short8*)&Qb[qbB + kk * 32 + lg * 8];
        }
    }

    float mA = -1e30f, lA = 0.f, mB = -1e30f, lB = 0.f;
    f32x4 oA[8] = {}, oB[8] = {};
    u16* Pw = &Pl[w][0];
    const int pwrow = lr * 64;
    const int lx = lr & 7;

#define STAGE(nb, kk0)                                                                   \
    {                                                                                    \
        _Pragma("unroll")                                                                \
        for (int i = 0; i < 2; ++i) {                                                    \
            int g = (w * 2 + i) * 64 + lane;                                             \
            int row = g >> 4, cp = g & 15;                                               \
            int c = cp ^ (row & 7);                                                      \
            const u16* src = Kb + ((size_t)(b * SEQ + (kk0) + row) * 1024 + h * 128 + c * 8); \
            GLL16(src, &Kbuf[nb][(w * 2 + i) * 512]);                                    \
        }                                                                                \
        _Pragma("unroll")                                                                \
        for (int i = 0; i < 2; ++i) {                                                    \
            int g = (w * 2 + i) * 64 + lane;                                             \
            int d = g >> 3, cp = g & 7;                                                  \
            int c = cp ^ (d & 7);                                                        \
            const u16* src = Vt + ((size_t)(bh * 128 + d) * 1024 + (kk0) + c * 8);       \
            GLL16(src, &Vbuf[nb][(w * 2 + i) * 512]);                                    \
        }                                                                                \
    }

    STAGE(0, 0);
    __syncthreads();

    int cur = 0;
    for (int k0 = 0; k0 < SEQ; k0 += 64) {
        if (k0 + 64 < SEQ) STAGE(cur ^ 1, k0 + 64);

        const u16* Kc = &Kbuf[cur][0];
        f32x4 sA[4] = {}, sB[4] = {};
        __builtin_amdgcn_s_setprio(1);
#pragma unroll
        for (int fn = 0; fn < 4; ++fn) {
            int krow = (fn * 16 + lr) * 128;
#pragma unroll
            for (int kk = 0; kk < 4; ++kk) {
                short8 kf = *(const short8*)&Kc[krow + (((kk * 4 + lg) ^ lx) << 3)];
                sA[fn] = __builtin_amdgcn_mfma_f32_16x16x32_bf16(kf, qfA[kk], sA[fn], 0, 0, 0);
                sB[fn] = __builtin_amdgcn_mfma_f32_16x16x32_bf16(kf, qfB[kk], sB[fn], 0, 0, 0);
            }
        }
        __builtin_amdgcn_s_setprio(0);

        short8 pfA0, pfA1, pfB0, pfB1;
        // ---- softmax set A -> P write -> immediate frag read (Pw reused) ----
        {
            float pm0 = fmaxf(fmaxf(sA[0][0], sA[0][1]), fmaxf(sA[0][2], sA[0][3]));
            float pm1 = fmaxf(fmaxf(sA[1][0], sA[1][1]), fmaxf(sA[1][2], sA[1][3]));
            float pm2 = fmaxf(fmaxf(sA[2][0], sA[2][1]), fmaxf(sA[2][2], sA[2][3]));
            float pm3 = fmaxf(fmaxf(sA[3][0], sA[3][1]), fmaxf(sA[3][2], sA[3][3]));
            float pmax = fmaxf(fmaxf(pm0, pm1), fmaxf(pm2, pm3));
            if (__any(pmax > mA + 11.5416f)) {
                float rm = pmax;
                rm = fmaxf(rm, __shfl_xor(rm, 16));
                rm = fmaxf(rm, __shfl_xor(rm, 32));
                float mnew = fmaxf(mA, rm);
                float alpha = exp2_fast(mA - mnew);
                mA = mnew;
                lA *= alpha;
#pragma unroll
                for (int db = 0; db < 8; ++db) oA[db] *= alpha;
            }
            float p[4][4];
            float ls0 = 0.f, ls1 = 0.f, ls2 = 0.f, ls3 = 0.f;
#pragma unroll
            for (int j = 0; j < 4; ++j) {
                p[0][j] = exp2_fast(sA[0][j] - mA); ls0 += p[0][j];
                p[1][j] = exp2_fast(sA[1][j] - mA); ls1 += p[1][j];
                p[2][j] = exp2_fast(sA[2][j] - mA); ls2 += p[2][j];
                p[3][j] = exp2_fast(sA[3][j] - mA); ls3 += p[3][j];
            }
            lA += (ls0 + ls1) + (ls2 + ls3);
#pragma unroll
            for (int fn = 0; fn < 4; ++fn) {
                uint2 pk;
                pk.x = cvtpk_bf16(p[fn][0], p[fn][1]);
                pk.y = cvtpk_bf16(p[fn][2], p[fn][3]);
                int idx = pwrow + (((fn * 2 + (lg >> 1)) ^ lx) << 3) + ((lg & 1) << 2);
                *(uint2*)&Pw[idx] = pk;
            }
            pfA0 = *(const short8*)&Pw[pwrow + ((lg ^ lx) << 3)];
            pfA1 = *(const short8*)&Pw[pwrow + (((4 + lg) ^ lx) << 3)];
        }
        // ---- softmax set B -> P write (same buffer) -> frag read ----
        {
            float pm0 = fmaxf(fmaxf(sB[0][0], sB[0][1]), fmaxf(sB[0][2], sB[0][3]));
            float pm1 = fmaxf(fmaxf(sB[1][0], sB[1][1]), fmaxf(sB[1][2], sB[1][3]));
            float pm2 = fmaxf(fmaxf(sB[2][0], sB[2][1]), fmaxf(sB[2][2], sB[2][3]));
            float pm3 = fmaxf(fmaxf(sB[3][0], sB[3][1]), fmaxf(sB[3][2], sB[3][3]));
            float pmax = fmaxf(fmaxf(pm0, pm1), fmaxf(pm2, pm3));
            if (__any(pmax > mB + 11.5416f)) {
                float rm = pmax;
                rm = fmaxf(rm, __shfl_xor(rm, 16));
                rm = fmaxf(rm, __shfl_xor(rm, 32));
                float mnew = fmaxf(mB, rm);
                float alpha = exp2_fast(mB - mnew);
                mB = mnew;
                lB *= alpha;
#pragma unroll
                for (int db = 0; db < 8; ++db) oB[db] *= alpha;
            }
            float p[4][4];
            float ls0 = 0.f, ls1 = 0.f, ls2 = 0.f, ls3 = 0.f;
#pragma unroll
            for (int j = 0; j < 4; ++j) {
                p[0][j] = exp2_fast(sB[0][j] - mB); ls0 += p[0][j];
                p[1][j] = exp2_fast(sB[1][j] - mB); ls1 += p[1][j];
                p[2][j] = exp2_fast(sB[2][j] - mB); ls2 += p[2][j];
                p[3][j] = exp2_fast(sB[3][j] - mB); ls3 += p[3][j];
            }
            lB += (ls0 + ls1) + (ls2 + ls3);
#pragma unroll
            for (int fn = 0; fn < 4; ++fn) {
                uint2 pk;
                pk.x = cvtpk_bf16(p[fn][0], p[fn][1]);
                pk.y = cvtpk_bf16(p[fn][2], p[fn][3]);
                int idx = pwrow + (((fn * 2 + (lg >> 1)) ^ lx) << 3) + ((lg & 1) << 2);
                *(uint2*)&Pw[idx] = pk;
            }
            pfB0 = *(const short8*)&Pw[pwrow + ((lg ^ lx) << 3)];
            pfB1 = *(const short8*)&Pw[pwrow + (((4 + lg) ^ lx) << 3)];
        }

        const u16* Vc = &Vbuf[cur][0];
        __builtin_amdgcn_s_setprio(1);
#pragma unroll
        for (int db = 0; db < 8; ++db) {
            int vr = (db * 16 + lr) * 64;
            short8 v0 = *(const short8*)&Vc[vr + ((lg ^ lx) << 3)];
            short8 v1 = *(const short8*)&Vc[vr + (((4 + lg) ^ lx) << 3)];
            oA[db] = __builtin_amdgcn_mfma_f32_16x16x32_bf16(v0, pfA0, oA[db], 0, 0, 0);
            oA[db] = __builtin_amdgcn_mfma_f32_16x16x32_bf16(v1, pfA1, oA[db], 0, 0, 0);
            oB[db] = __builtin_amdgcn_mfma_f32_16x16x32_bf16(v0, pfB0, oB[db], 0, 0, 0);
            oB[db] = __builtin_amdgcn_mfma_f32_16x16x32_bf16(v1, pfB1, oB[db], 0, 0, 0);
        }
        __builtin_amdgcn_s_setprio(0);

        __syncthreads();
        cur ^= 1;
    }

    float ltA = lA;
    ltA += __shfl_xor(ltA, 16);
    ltA += __shfl_xor(ltA, 32);
    float invA = 1.f / ltA;
    float ltB = lB;
    ltB += __shfl_xor(ltB, 16);
    ltB += __shfl_xor(ltB, 32);
    float invB = 1.f / ltB;
    size_t obaseA = (size_t)(b * SEQ + q0 + w * 32 + lr) * 1024 + h * DHEAD + lg * 4;
    size_t obaseB = obaseA + (size_t)16 * 1024;
    if (AOb) {
#pragma unroll
        for (int db = 0; db < 8; ++db) {
            uint2 pa, pb2;
            pa.x = cvtpk_bf16(oA[db][0] * invA, oA[db][1] * invA);
            pa.y = cvtpk_bf16(oA[db][2] * invA, oA[db][3] * invA);
            pb2.x = cvtpk_bf16(oB[db][0] * invB, oB[db][1] * invB);
            pb2.y = cvtpk_bf16(oB[db][2] * invB, oB[db][3] * invB);
            *(uint2*)&AOb[obaseA + db * 16] = pa;
            *(uint2*)&AOb[obaseB + db * 16] = pb2;
        }
    } else {
#pragma unroll
        for (int db = 0; db < 8; ++db) {
            float4 ov;
            ov.x = oA[db][0] * invA;
            ov.y = oA[db][1] * invA;
            ov.z = oA[db][2] * invA;
            ov.w = oA[db][3] * invA;
            *(float4*)&AO[obaseA + db * 16] = ov;
            float4 ow;
            ow.x = oB[db][0] * invB;
            ow.y = oB[db][1] * invB;
            ow.z = oB[db][2] * invB;
            ow.w = oB[db][3] * invB;
            *(float4*)&AO[obaseB + db * 16] = ow;
        }
    }
#undef STAGE
}

// ---------------------------------------------------------------------------
// Kernel 4: residual blend + LayerNorm. AO from bf16 (AOb) if provided, else
// fp32 (AOf). q from bf16 (qbb, in ws) if provided, else fp32 (qin).
// ---------------------------------------------------------------------------
__global__ __launch_bounds__(256) void ln_kernel(const float* __restrict__ AOf,
                                                 const u16* __restrict__ AOb,
                                                 const float* __restrict__ qin,
                                                 const u16* __restrict__ qbb,
                                                 const float* __restrict__ gamma,
                                                 const float* __restrict__ beta,
                                                 float* __restrict__ out) {
    __shared__ float red[8];
    int row = blockIdx.x;
    int t = threadIdx.x;
    size_t base = (size_t)row * 1024 + t * 4;

    float a0, a1, a2, a3;
    if (AOb) {
        ushort4 u = *(const ushort4*)&AOb[base];
        union { uint32_t i; float f; } c0, c1, c2, c3;
        c0.i = (uint32_t)u.x << 16; c1.i = (uint32_t)u.y << 16;
        c2.i = (uint32_t)u.z << 16; c3.i = (uint32_t)u.w << 16;
        a0 = c0.f; a1 = c1.f; a2 = c2.f; a3 = c3.f;
    } else {
        float4 a = *(const float4*)&AOf[base];
        a0 = a.x; a1 = a.y; a2 = a.z; a3 = a.w;
    }
    float q0v, q1v, q2v, q3v;
    if (qbb) {
        ushort4 u = *(const ushort4*)&qbb[base];
        union { uint32_t i; float f; } c0, c1, c2, c3;
        c0.i = (uint32_t)u.x << 16; c1.i = (uint32_t)u.y << 16;
        c2.i = (uint32_t)u.z << 16; c3.i = (uint32_t)u.w << 16;
        q0v = c0.f; q1v = c1.f; q2v = c2.f; q3v = c3.f;
    } else {
        float4 qq = *(const float4*)&qin[base];
        q0v = qq.x; q1v = qq.y; q2v = qq.z; q3v = qq.w;
    }
    float x0 = a0 * 0.1f + q0v * 0.9f;
    float x1 = a1 * 0.1f + q1v * 0.9f;
    float x2 = a2 * 0.1f + q2v * 0.9f;
    float x3 = a3 * 0.1f + q3v * 0.9f;

    float s  = x0 + x1 + x2 + x3;
    float s2 = x0 * x0 + x1 * x1 + x2 * x2 + x3 * x3;
    for (int d = 1; d < 64; d <<= 1) {
        s  += __shfl_xor(s, d);
        s2 += __shfl_xor(s2, d);
    }
    int w = t >> 6, lane = t & 63;
    if (lane == 0) { red[w] = s; red[4 + w] = s2; }
    __syncthreads();
    s  = red[0] + red[1] + red[2] + red[3];
    s2 = red[4] + red[5] + red[6] + red[7];

    float mu   = s * (1.f / 1024.f);
    float var  = s2 * (1.f / 1024.f) - mu * mu;
    float rstd = rsqrtf(var + 1e-5f);

    float4 g  = *(const float4*)&gamma[t * 4];
    float4 be = *(const float4*)&beta[t * 4];
    float4 o;
    o.x = (x0 - mu) * rstd * g.x + be.x;
    o.y = (x1 - mu) * rstd * g.y + be.y;
    o.z = (x2 - mu) * rstd * g.z + be.z;
    o.w = (x3 - mu) * rstd * g.w + be.w;
    *(float4*)&out[base] = o;
}

// ---------------------------------------------------------------------------
extern "C" void kernel_launch(void* const* d_in, const int* in_sizes, int n_in,
                              void* d_out, int out_size, void* d_ws, size_t ws_size,
                              hipStream_t stream) {
    const float* q     = (const float*)d_in[0];
    const float* k     = (const float*)d_in[1];
    const float* Wq    = (const float*)d_in[2];
    const float* bq    = (const float*)d_in[3];
    const float* Wk    = (const float*)d_in[4];
    const float* bk    = (const float*)d_in[5];
    const float* gamma = (const float*)d_in[6];
    const float* beta  = (const float*)d_in[7];
    float* out = (float*)d_out;

    char* ws = (char*)d_ws;
    u16* WqT = (u16*)ws;                             // 2 MB
    u16* WkT = (u16*)(ws + (size_t)(2  << 20));      // 2 MB
    u16* Qb  = (u16*)(ws + (size_t)(4  << 20));      // 16 MB
    u16* Kb  = (u16*)(ws + (size_t)(20 << 20));      // 16 MB
    u16* Vt  = (u16*)(ws + (size_t)(36 << 20));      // 16 MB  (52 MB)
    // optional bf16 attention output (saves 32 MB HBM round-trip into LN)
    u16* AOb = (ws_size >= ((size_t)68 << 20)) ? (u16*)(ws + ((size_t)52 << 20)) : nullptr;
    // optional qb in ws (lets LN read bf16 q: saves another 16 MB in LN)
    u16* qbw = (ws_size >= ((size_t)84 << 20)) ? (u16*)(ws + ((size_t)68 << 20)) : nullptr;

    // d_out doubles as bf16 scratch until attn/LN overwrite it
    u16* qb = qbw ? qbw : (u16*)d_out;               // 8M elems
    u16* kb = qbw ? (u16*)d_out : ((u16*)d_out + (size_t)8 * 1024 * 1024);

    // 1) W transposes + k -> (Vt, kb) + q -> qb, one pass
    transpose_conv<<<dim3(32, 32, 2 + BATCH), dim3(32, 8), 0, stream>>>(Wq, Wk, k, q, WqT, WkT, Vt, kb, qb);

    // 2) both projections in one launch (Q pre-scaled by log2e/sqrt(DH))
    gemm_dual<<<1024, 256, 0, stream>>>(qb, kb, WqT, WkT, bq, bk, Qb, Kb);

    // 3) attention (80KB LDS -> 2 blocks/CU; bf16 AO into ws if space allows)
    attn_kernel<<<256, 512, 0, stream>>>(Qb, Kb, Vt, out, AOb);

    // 4) residual + layernorm -> d_out (q from bf16 if qb lives in ws)
    ln_kernel<<<8192, 256, 0, stream>>>(out, AOb, q, qbw, gamma, beta, out);
}

// Round 16
// 126.925 us; speedup vs baseline: 1.8513x; 1.8513x over previous
//
#include <hip/hip_runtime.h>
#include <hip/hip_bf16.h>
#include <cstdint>

// Problem constants
#define BATCH 8
#define SEQ   1024          // LQ == LK
#define DMODEL 1024
#define NHEAD 8
#define DHEAD 128

using short8 = __attribute__((ext_vector_type(8))) short;
using f32x4  = __attribute__((ext_vector_type(4))) float;
typedef unsigned short u16;

__device__ inline u16 f2bf(float f) {
    union { float f; uint32_t u; } v; v.f = f;
    uint32_t r = (v.u + 0x7FFFu + ((v.u >> 16) & 1u)) >> 16;
    return (u16)r;
}

// native 2^x (v_exp_f32)
__device__ inline float exp2_fast(float x) { return __builtin_amdgcn_exp2f(x); }

// packed f32x2 -> bf16x2 (RNE), low half = a
__device__ inline uint32_t cvtpk_bf16(float a, float b) {
    uint32_t r;
    asm("v_cvt_pk_bf16_f32 %0, %1, %2" : "=v"(r) : "v"(a), "v"(b));
    return r;
}

// async global->LDS, 16B per lane. LDS dest is wave-uniform base; HW adds lane*16.
#define GLL16(g, l)                                                                        \
    __builtin_amdgcn_global_load_lds((__attribute__((address_space(1))) const uint32_t*)(g), \
                                     (__attribute__((address_space(3))) uint32_t*)(l), 16, 0, 0)

// ---------------------------------------------------------------------------
// Kernel 1: prep pass.
// z=0: Wq -> WqT ; z=1: Wk -> WkT ; z>=2: k[b] -> Vt[b] (transpose) AND
// k[b] -> kb[b] (bf16 copy) AND q[b] -> qb[b] (bf16 copy).
// ---------------------------------------------------------------------------
__global__ void transpose_conv(const float* __restrict__ Wq,
                               const float* __restrict__ Wk,
                               const float* __restrict__ kin,
                               const float* __restrict__ qin,
                               u16* __restrict__ WqT,
                               u16* __restrict__ WkT,
                               u16* __restrict__ Vt,
                               u16* __restrict__ kb,
                               u16* __restrict__ qb) {
    __shared__ float tile[32][33];
    int z = blockIdx.z;
    const float* src;
    u16* dst;
    u16* sdst = nullptr;
    const float* qsrc = nullptr;
    u16* qdst = nullptr;
    if (z == 0)      { src = Wq; dst = WqT; }
    else if (z == 1) { src = Wk; dst = WkT; }
    else {
        size_t off = (size_t)(z - 2) * DMODEL * SEQ;
        src  = kin + off;
        dst  = Vt  + off;
        sdst = kb  + off;
        qsrc = qin + off;
        qdst = qb  + off;
    }
    int x  = blockIdx.x * 32 + threadIdx.x;
    int y0 = blockIdx.y * 32;
    for (int i = threadIdx.y; i < 32; i += 8) {
        float v = src[(size_t)(y0 + i) * 1024 + x];
        tile[i][threadIdx.x] = v;
        if (sdst) sdst[(size_t)(y0 + i) * 1024 + x] = f2bf(v);
    }
    if (qsrc) {
        for (int i = threadIdx.y; i < 32; i += 8)
            qdst[(size_t)(y0 + i) * 1024 + x] = f2bf(qsrc[(size_t)(y0 + i) * 1024 + x]);
    }
    __syncthreads();
    int xo  = y0 + threadIdx.x;
    int yo0 = blockIdx.x * 32;
    for (int i = threadIdx.y; i < 32; i += 8)
        dst[(size_t)(yo0 + i) * 1024 + xo] = f2bf(tile[threadIdx.x][i]);
}

// ---------------------------------------------------------------------------
// Kernel 2: fused dual GEMM (m97 structure, proven). 128x128 tile, BK=32,
// both operands global_load_lds w16, dbuf, 1 barrier/iter, XOR swizzle.
// blocks 0..511: Q-proj (scale=log2e/sqrt(DH)); 512..1023: K-proj.
// ---------------------------------------------------------------------------
__global__ __launch_bounds__(256, 4) void gemm_dual(const u16* __restrict__ Aq,
                                                    const u16* __restrict__ Ak,
                                                    const u16* __restrict__ BTq,
                                                    const u16* __restrict__ BTk,
                                                    const float* __restrict__ biasq,
                                                    const float* __restrict__ biask,
                                                    u16* __restrict__ Outq,
                                                    u16* __restrict__ Outk) {
    __shared__ __align__(16) u16 As[2][128 * 32];
    __shared__ __align__(16) u16 Bs[2][128 * 32];

    int bid = blockIdx.x;
    int half = bid >> 9;
    int b2 = bid & 511;
    const u16* A  = half ? Ak  : Aq;
    const u16* BT = half ? BTk : BTq;
    const float* bias = half ? biask : biasq;
    u16* Out = half ? Outk : Outq;
    float scale = half ? 1.0f : (0.08838834764831845f * 1.4426950408889634f);

    int swz = (b2 & 7) * 64 + (b2 >> 3);
    int mt = swz >> 3, nt = swz & 7;
    int m0 = mt * 128, n0 = nt * 128;

    int t = threadIdx.x, lane = t & 63, w = t >> 6;
    int wm = w >> 1, wn = w & 1;
    int lr = lane & 15, lg = lane >> 4;

    const u16* pa[2];
    const u16* pb[2];
#pragma unroll
    for (int i = 0; i < 2; ++i) {
        int L = (w * 2 + i) * 64 + lane;
        int rp = L >> 3, ss = L & 7;
        int u = ss ^ (rp & 7);
        int row = (rp << 1) | (u >> 2);
        int g = u & 3;
        pa[i] = A  + (size_t)(m0 + row) * 1024 + g * 8;
        pb[i] = BT + (size_t)(n0 + row) * 1024 + g * 8;
    }
    int aoff[4], boff[4];
#pragma unroll
    for (int f = 0; f < 4; ++f) {
        int rowA = wm * 64 + f * 16 + lr;
        int sA = (((rowA & 1) << 2) | lg) ^ ((rowA >> 1) & 7);
        aoff[f] = (rowA >> 1) * 64 + sA * 8;
        int rowB = wn * 64 + f * 16 + lr;
        int sB = (((rowB & 1) << 2) | lg) ^ ((rowB >> 1) & 7);
        boff[f] = (rowB >> 1) * 64 + sB * 8;
    }

    f32x4 acc[4][4] = {};

#define GSTAGE(buf)                                         \
    {                                                       \
        _Pragma("unroll")                                   \
        for (int i = 0; i < 2; ++i) {                       \
            GLL16(pa[i], &As[buf][(w * 2 + i) * 512]);      \
            GLL16(pb[i], &Bs[buf][(w * 2 + i) * 512]);      \
            pa[i] += 32;                                    \
            pb[i] += 32;                                    \
        }                                                   \
    }

    GSTAGE(0);
    __syncthreads();

    int cur = 0;
    for (int k0 = 0; k0 < DMODEL; k0 += 32) {
        if (k0 + 32 < DMODEL) GSTAGE(cur ^ 1);
        short8 af[4], bfr[4];
#pragma unroll
        for (int f = 0; f < 4; ++f) {
            af[f]  = *(const short8*)&As[cur][aoff[f]];
            bfr[f] = *(const short8*)&Bs[cur][boff[f]];
        }
        __builtin_amdgcn_s_setprio(1);
#pragma unroll
        for (int fm = 0; fm < 4; ++fm)
#pragma unroll
            for (int fn = 0; fn < 4; ++fn)
                acc[fm][fn] = __builtin_amdgcn_mfma_f32_16x16x32_bf16(af[fm], bfr[fn], acc[fm][fn], 0, 0, 0);
        __builtin_amdgcn_s_setprio(0);
        __syncthreads();
        cur ^= 1;
    }
#undef GSTAGE

#pragma unroll
    for (int fn = 0; fn < 4; ++fn) {
        int col = n0 + wn * 64 + fn * 16 + lr;
        float bv = bias[col];
#pragma unroll
        for (int fm = 0; fm < 4; ++fm)
#pragma unroll
            for (int j = 0; j < 4; ++j) {
                int row = m0 + wm * 64 + fm * 16 + lg * 4 + j;
                Out[(size_t)row * 1024 + col] = f2bf((acc[fm][fn][j] + bv) * scale);
            }
    }
}

// ---------------------------------------------------------------------------
// Kernel 3: flash attention (r11/r14 proven structure: 8 waves x 32 q-rows,
// swapped-QK^T, exp2-domain, deferred softmax, dbuf global_load_lds, bf16 AO).
// launch_bounds(512,2): 1 block/CU — the register footprint (64 acc + 32 qf
// + 32 s) cannot fit 2 blocks/CU (r15 lesson: forcing it spills to scratch).
// ---------------------------------------------------------------------------
__global__ __launch_bounds__(512, 2) void attn_kernel(const u16* __restrict__ Qb,
                                                      const u16* __restrict__ Kb,
                                                      const u16* __restrict__ Vt,
                                                      float* __restrict__ AO,
                                                      u16* __restrict__ AOb) {
    __shared__ __align__(16) u16 Kbuf[2][64 * 128];   // 32 KB
    __shared__ __align__(16) u16 Vbuf[2][128 * 64];   // 32 KB
    __shared__ __align__(16) u16 Pl[8][2][16 * 64];   // 32 KB

    int bid = blockIdx.x;
    int swz = (bid & 7) * 32 + (bid >> 3);
    int bh  = swz >> 2;
    int qt  = swz & 3;
    int b = bh >> 3, h = bh & 7;
    int q0 = qt * 256;

    int t = threadIdx.x, lane = t & 63, w = t >> 6;
    int lr = lane & 15, lg = lane >> 4;

    short8 qfA[4], qfB[4];
    {
        size_t qa = (size_t)(b * SEQ + q0 + w * 32 + lr) * 1024 + h * DHEAD;
        size_t qbB = qa + (size_t)16 * 1024;
#pragma unroll
        for (int kk = 0; kk < 4; ++kk) {
            qfA[kk] = *(const short8*)&Qb[qa  + kk * 32 + lg * 8];
            qfB[kk] = *(const short8*)&Qb[qbB + kk * 32 + lg * 8];
        }
    }

    float mA = -1e30f, lA = 0.f, mB = -1e30f, lB = 0.f;
    f32x4 oA[8] = {}, oB[8] = {};
    u16* PwA = &Pl[w][0][0];
    u16* PwB = &Pl[w][1][0];
    const int pwrow = lr * 64;
    const int lx = lr & 7;

#define STAGE(nb, kk0)                                                                   \
    {                                                                                    \
        _Pragma("unroll")                                                                \
        for (int i = 0; i < 2; ++i) {                                                    \
            int g = (w * 2 + i) * 64 + lane;                                             \
            int row = g >> 4, cp = g & 15;                                               \
            int c = cp ^ (row & 7);                                                      \
            const u16* src = Kb + ((size_t)(b * SEQ + (kk0) + row) * 1024 + h * 128 + c * 8); \
            GLL16(src, &Kbuf[nb][(w * 2 + i) * 512]);                                    \
        }                                                                                \
        _Pragma("unroll")                                                                \
        for (int i = 0; i < 2; ++i) {                                                    \
            int g = (w * 2 + i) * 64 + lane;                                             \
            int d = g >> 3, cp = g & 7;                                                  \
            int c = cp ^ (d & 7);                                                        \
            const u16* src = Vt + ((size_t)(bh * 128 + d) * 1024 + (kk0) + c * 8);       \
            GLL16(src, &Vbuf[nb][(w * 2 + i) * 512]);                                    \
        }                                                                                \
    }

    STAGE(0, 0);
    __syncthreads();

    int cur = 0;
    for (int k0 = 0; k0 < SEQ; k0 += 64) {
        if (k0 + 64 < SEQ) STAGE(cur ^ 1, k0 + 64);

        const u16* Kc = &Kbuf[cur][0];
        f32x4 sA[4] = {}, sB[4] = {};
        __builtin_amdgcn_s_setprio(1);
#pragma unroll
        for (int fn = 0; fn < 4; ++fn) {
            int krow = (fn * 16 + lr) * 128;
#pragma unroll
            for (int kk = 0; kk < 4; ++kk) {
                short8 kf = *(const short8*)&Kc[krow + (((kk * 4 + lg) ^ lx) << 3)];
                sA[fn] = __builtin_amdgcn_mfma_f32_16x16x32_bf16(kf, qfA[kk], sA[fn], 0, 0, 0);
                sB[fn] = __builtin_amdgcn_mfma_f32_16x16x32_bf16(kf, qfB[kk], sB[fn], 0, 0, 0);
            }
        }
        __builtin_amdgcn_s_setprio(0);

        {
            float pm0 = fmaxf(fmaxf(sA[0][0], sA[0][1]), fmaxf(sA[0][2], sA[0][3]));
            float pm1 = fmaxf(fmaxf(sA[1][0], sA[1][1]), fmaxf(sA[1][2], sA[1][3]));
            float pm2 = fmaxf(fmaxf(sA[2][0], sA[2][1]), fmaxf(sA[2][2], sA[2][3]));
            float pm3 = fmaxf(fmaxf(sA[3][0], sA[3][1]), fmaxf(sA[3][2], sA[3][3]));
            float pmax = fmaxf(fmaxf(pm0, pm1), fmaxf(pm2, pm3));
            if (__any(pmax > mA + 11.5416f)) {
                float rm = pmax;
                rm = fmaxf(rm, __shfl_xor(rm, 16));
                rm = fmaxf(rm, __shfl_xor(rm, 32));
                float mnew = fmaxf(mA, rm);
                float alpha = exp2_fast(mA - mnew);
                mA = mnew;
                lA *= alpha;
#pragma unroll
                for (int db = 0; db < 8; ++db) oA[db] *= alpha;
            }
            float p[4][4];
            float ls0 = 0.f, ls1 = 0.f, ls2 = 0.f, ls3 = 0.f;
#pragma unroll
            for (int j = 0; j < 4; ++j) {
                p[0][j] = exp2_fast(sA[0][j] - mA); ls0 += p[0][j];
                p[1][j] = exp2_fast(sA[1][j] - mA); ls1 += p[1][j];
                p[2][j] = exp2_fast(sA[2][j] - mA); ls2 += p[2][j];
                p[3][j] = exp2_fast(sA[3][j] - mA); ls3 += p[3][j];
            }
            lA += (ls0 + ls1) + (ls2 + ls3);
#pragma unroll
            for (int fn = 0; fn < 4; ++fn) {
                uint2 pk;
                pk.x = cvtpk_bf16(p[fn][0], p[fn][1]);
                pk.y = cvtpk_bf16(p[fn][2], p[fn][3]);
                int idx = pwrow + (((fn * 2 + (lg >> 1)) ^ lx) << 3) + ((lg & 1) << 2);
                *(uint2*)&PwA[idx] = pk;
            }
        }
        {
            float pm0 = fmaxf(fmaxf(sB[0][0], sB[0][1]), fmaxf(sB[0][2], sB[0][3]));
            float pm1 = fmaxf(fmaxf(sB[1][0], sB[1][1]), fmaxf(sB[1][2], sB[1][3]));
            float pm2 = fmaxf(fmaxf(sB[2][0], sB[2][1]), fmaxf(sB[2][2], sB[2][3]));
            float pm3 = fmaxf(fmaxf(sB[3][0], sB[3][1]), fmaxf(sB[3][2], sB[3][3]));
            float pmax = fmaxf(fmaxf(pm0, pm1), fmaxf(pm2, pm3));
            if (__any(pmax > mB + 11.5416f)) {
                float rm = pmax;
                rm = fmaxf(rm, __shfl_xor(rm, 16));
                rm = fmaxf(rm, __shfl_xor(rm, 32));
                float mnew = fmaxf(mB, rm);
                float alpha = exp2_fast(mB - mnew);
                mB = mnew;
                lB *= alpha;
#pragma unroll
                for (int db = 0; db < 8; ++db) oB[db] *= alpha;
            }
            float p[4][4];
            float ls0 = 0.f, ls1 = 0.f, ls2 = 0.f, ls3 = 0.f;
#pragma unroll
            for (int j = 0; j < 4; ++j) {
                p[0][j] = exp2_fast(sB[0][j] - mB); ls0 += p[0][j];
                p[1][j] = exp2_fast(sB[1][j] - mB); ls1 += p[1][j];
                p[2][j] = exp2_fast(sB[2][j] - mB); ls2 += p[2][j];
                p[3][j] = exp2_fast(sB[3][j] - mB); ls3 += p[3][j];
            }
            lB += (ls0 + ls1) + (ls2 + ls3);
#pragma unroll
            for (int fn = 0; fn < 4; ++fn) {
                uint2 pk;
                pk.x = cvtpk_bf16(p[fn][0], p[fn][1]);
                pk.y = cvtpk_bf16(p[fn][2], p[fn][3]);
                int idx = pwrow + (((fn * 2 + (lg >> 1)) ^ lx) << 3) + ((lg & 1) << 2);
                *(uint2*)&PwB[idx] = pk;
            }
        }

        const u16* Vc = &Vbuf[cur][0];
        short8 pfA0 = *(const short8*)&PwA[pwrow + ((lg ^ lx) << 3)];
        short8 pfA1 = *(const short8*)&PwA[pwrow + (((4 + lg) ^ lx) << 3)];
        short8 pfB0 = *(const short8*)&PwB[pwrow + ((lg ^ lx) << 3)];
        short8 pfB1 = *(const short8*)&PwB[pwrow + (((4 + lg) ^ lx) << 3)];
        __builtin_amdgcn_s_setprio(1);
#pragma unroll
        for (int db = 0; db < 8; ++db) {
            int vr = (db * 16 + lr) * 64;
            short8 v0 = *(const short8*)&Vc[vr + ((lg ^ lx) << 3)];
            short8 v1 = *(const short8*)&Vc[vr + (((4 + lg) ^ lx) << 3)];
            oA[db] = __builtin_amdgcn_mfma_f32_16x16x32_bf16(v0, pfA0, oA[db], 0, 0, 0);
            oA[db] = __builtin_amdgcn_mfma_f32_16x16x32_bf16(v1, pfA1, oA[db], 0, 0, 0);
            oB[db] = __builtin_amdgcn_mfma_f32_16x16x32_bf16(v0, pfB0, oB[db], 0, 0, 0);
            oB[db] = __builtin_amdgcn_mfma_f32_16x16x32_bf16(v1, pfB1, oB[db], 0, 0, 0);
        }
        __builtin_amdgcn_s_setprio(0);

        __syncthreads();
        cur ^= 1;
    }

    float ltA = lA;
    ltA += __shfl_xor(ltA, 16);
    ltA += __shfl_xor(ltA, 32);
    float invA = 1.f / ltA;
    float ltB = lB;
    ltB += __shfl_xor(ltB, 16);
    ltB += __shfl_xor(ltB, 32);
    float invB = 1.f / ltB;
    size_t obaseA = (size_t)(b * SEQ + q0 + w * 32 + lr) * 1024 + h * DHEAD + lg * 4;
    size_t obaseB = obaseA + (size_t)16 * 1024;
    if (AOb) {
#pragma unroll
        for (int db = 0; db < 8; ++db) {
            uint2 pa, pb2;
            pa.x = cvtpk_bf16(oA[db][0] * invA, oA[db][1] * invA);
            pa.y = cvtpk_bf16(oA[db][2] * invA, oA[db][3] * invA);
            pb2.x = cvtpk_bf16(oB[db][0] * invB, oB[db][1] * invB);
            pb2.y = cvtpk_bf16(oB[db][2] * invB, oB[db][3] * invB);
            *(uint2*)&AOb[obaseA + db * 16] = pa;
            *(uint2*)&AOb[obaseB + db * 16] = pb2;
        }
    } else {
#pragma unroll
        for (int db = 0; db < 8; ++db) {
            float4 ov;
            ov.x = oA[db][0] * invA;
            ov.y = oA[db][1] * invA;
            ov.z = oA[db][2] * invA;
            ov.w = oA[db][3] * invA;
            *(float4*)&AO[obaseA + db * 16] = ov;
            float4 ow;
            ow.x = oB[db][0] * invB;
            ow.y = oB[db][1] * invB;
            ow.z = oB[db][2] * invB;
            ow.w = oB[db][3] * invB;
            *(float4*)&AO[obaseB + db * 16] = ow;
        }
    }
#undef STAGE
}

// ---------------------------------------------------------------------------
// Kernel 4: residual blend + LayerNorm. AO from bf16 (AOb) if provided, else
// fp32 (AOf). q from bf16 (qbb, in ws) if provided, else fp32 (qin).
// ---------------------------------------------------------------------------
__global__ __launch_bounds__(256) void ln_kernel(const float* __restrict__ AOf,
                                                 const u16* __restrict__ AOb,
                                                 const float* __restrict__ qin,
                                                 const u16* __restrict__ qbb,
                                                 const float* __restrict__ gamma,
                                                 const float* __restrict__ beta,
                                                 float* __restrict__ out) {
    __shared__ float red[8];
    int row = blockIdx.x;
    int t = threadIdx.x;
    size_t base = (size_t)row * 1024 + t * 4;

    float a0, a1, a2, a3;
    if (AOb) {
        ushort4 u = *(const ushort4*)&AOb[base];
        union { uint32_t i; float f; } c0, c1, c2, c3;
        c0.i = (uint32_t)u.x << 16; c1.i = (uint32_t)u.y << 16;
        c2.i = (uint32_t)u.z << 16; c3.i = (uint32_t)u.w << 16;
        a0 = c0.f; a1 = c1.f; a2 = c2.f; a3 = c3.f;
    } else {
        float4 a = *(const float4*)&AOf[base];
        a0 = a.x; a1 = a.y; a2 = a.z; a3 = a.w;
    }
    float q0v, q1v, q2v, q3v;
    if (qbb) {
        ushort4 u = *(const ushort4*)&qbb[base];
        union { uint32_t i; float f; } c0, c1, c2, c3;
        c0.i = (uint32_t)u.x << 16; c1.i = (uint32_t)u.y << 16;
        c2.i = (uint32_t)u.z << 16; c3.i = (uint32_t)u.w << 16;
        q0v = c0.f; q1v = c1.f; q2v = c2.f; q3v = c3.f;
    } else {
        float4 qq = *(const float4*)&qin[base];
        q0v = qq.x; q1v = qq.y; q2v = qq.z; q3v = qq.w;
    }
    float x0 = a0 * 0.1f + q0v * 0.9f;
    float x1 = a1 * 0.1f + q1v * 0.9f;
    float x2 = a2 * 0.1f + q2v * 0.9f;
    float x3 = a3 * 0.1f + q3v * 0.9f;

    float s  = x0 + x1 + x2 + x3;
    float s2 = x0 * x0 + x1 * x1 + x2 * x2 + x3 * x3;
    for (int d = 1; d < 64; d <<= 1) {
        s  += __shfl_xor(s, d);
        s2 += __shfl_xor(s2, d);
    }
    int w = t >> 6, lane = t & 63;
    if (lane == 0) { red[w] = s; red[4 + w] = s2; }
    __syncthreads();
    s  = red[0] + red[1] + red[2] + red[3];
    s2 = red[4] + red[5] + red[6] + red[7];

    float mu   = s * (1.f / 1024.f);
    float var  = s2 * (1.f / 1024.f) - mu * mu;
    float rstd = rsqrtf(var + 1e-5f);

    float4 g  = *(const float4*)&gamma[t * 4];
    float4 be = *(const float4*)&beta[t * 4];
    float4 o;
    o.x = (x0 - mu) * rstd * g.x + be.x;
    o.y = (x1 - mu) * rstd * g.y + be.y;
    o.z = (x2 - mu) * rstd * g.z + be.z;
    o.w = (x3 - mu) * rstd * g.w + be.w;
    *(float4*)&out[base] = o;
}

// ---------------------------------------------------------------------------
extern "C" void kernel_launch(void* const* d_in, const int* in_sizes, int n_in,
                              void* d_out, int out_size, void* d_ws, size_t ws_size,
                              hipStream_t stream) {
    const float* q     = (const float*)d_in[0];
    const float* k     = (const float*)d_in[1];
    const float* Wq    = (const float*)d_in[2];
    const float* bq    = (const float*)d_in[3];
    const float* Wk    = (const float*)d_in[4];
    const float* bk    = (const float*)d_in[5];
    const float* gamma = (const float*)d_in[6];
    const float* beta  = (const float*)d_in[7];
    float* out = (float*)d_out;

    char* ws = (char*)d_ws;
    u16* WqT = (u16*)ws;                             // 2 MB
    u16* WkT = (u16*)(ws + (size_t)(2  << 20));      // 2 MB
    u16* Qb  = (u16*)(ws + (size_t)(4  << 20));      // 16 MB
    u16* Kb  = (u16*)(ws + (size_t)(20 << 20));      // 16 MB
    u16* Vt  = (u16*)(ws + (size_t)(36 << 20));      // 16 MB  (52 MB)
    // optional bf16 attention output (saves 32 MB HBM round-trip into LN)
    u16* AOb = (ws_size >= ((size_t)68 << 20)) ? (u16*)(ws + ((size_t)52 << 20)) : nullptr;
    // optional qb in ws (lets LN read bf16 q: saves another 16 MB in LN)
    u16* qbw = (ws_size >= ((size_t)84 << 20)) ? (u16*)(ws + ((size_t)68 << 20)) : nullptr;

    // d_out doubles as bf16 scratch until attn/LN overwrite it
    u16* qb = qbw ? qbw : (u16*)d_out;               // 8M elems
    u16* kb = qbw ? (u16*)d_out : ((u16*)d_out + (size_t)8 * 1024 * 1024);

    // 1) W transposes + k -> (Vt, kb) + q -> qb, one pass
    transpose_conv<<<dim3(32, 32, 2 + BATCH), dim3(32, 8), 0, stream>>>(Wq, Wk, k, q, WqT, WkT, Vt, kb, qb);

    // 2) both projections in one launch (Q pre-scaled by log2e/sqrt(DH))
    gemm_dual<<<1024, 256, 0, stream>>>(qb, kb, WqT, WkT, bq, bk, Qb, Kb);

    // 3) attention (bf16 AO into ws if space allows)
    attn_kernel<<<256, 512, 0, stream>>>(Qb, Kb, Vt, out, AOb);

    // 4) residual + layernorm -> d_out (q from bf16 if qb lives in ws)
    ln_kernel<<<8192, 256, 0, stream>>>(out, AOb, q, qbw, gamma, beta, out);
}